// Round 13
// baseline (184.765 us; speedup 1.0000x reference)
//
#include <hip/hip_runtime.h>
#include <hip/hip_bf16.h>

#define BB 4
#define CMv 256
#define CTv 64
#define CAv 128
#define NTOK 6400
#define KVSPLIT 5
#define KVRANGE 1280   /* NTOK/KVSPLIT */
#define NTILES 20      /* KVRANGE/64 */
/* 128^-0.5 * log2(e): softmax runs in exp2 domain */
#define QSCL 0.12753102198064644f

typedef unsigned short u16;
typedef __attribute__((ext_vector_type(8))) short sh8;     // 8 bf16
typedef __attribute__((ext_vector_type(4))) float f32x4;
typedef __attribute__((ext_vector_type(16))) float f32x16;
typedef __attribute__((ext_vector_type(4))) unsigned uint4v;
typedef __attribute__((ext_vector_type(2))) unsigned uint2v;

__device__ __forceinline__ u16 f2bf(float f) {
  return __builtin_bit_cast(u16, __float2bfloat16(f));
}
__device__ __forceinline__ float bf2f(u16 x) {
  unsigned u = ((unsigned)x) << 16;
  return __builtin_bit_cast(float, u);
}
__device__ __forceinline__ unsigned pk2(float a, float b) {
  return ((unsigned)f2bf(b) << 16) | (unsigned)f2bf(a);
}
__device__ __forceinline__ f32x16 zero16() {
  f32x16 z;
#pragma unroll
  for (int i = 0; i < 16; i++) z[i] = 0.f;
  return z;
}
typedef const __attribute__((address_space(1))) unsigned int* gas_p;
typedef __attribute__((address_space(3))) unsigned int* las_p;
__device__ __forceinline__ void gl_lds16(const u16* g, u16* l) {
  __builtin_amdgcn_global_load_lds((gas_p)g, (las_p)l, 16, 0, 0);
}

// ---------------- weight prep: fp32 -> bf16, row-major (A-frag ready) ----------------
__global__ __launch_bounds__(256) void prep(const float* __restrict__ wq,
                                            const float* __restrict__ bq,
                                            const float* __restrict__ wk,
                                            const float* __restrict__ wv,
                                            const float* __restrict__ wo,
                                            u16* __restrict__ wqB,
                                            float* __restrict__ bqs,
                                            u16* __restrict__ wkB,
                                            u16* __restrict__ wvB,
                                            u16* __restrict__ woB) {
  const int i0 = blockIdx.x * 256 + threadIdx.x;
  const int stride = gridDim.x * 256;
  for (int i = i0; i < 128 * 256; i += stride) wqB[i] = f2bf(wq[i] * QSCL);
  for (int i = i0; i < 128 * 64; i += stride) { wkB[i] = f2bf(wk[i]); wvB[i] = f2bf(wv[i]); }
  for (int i = i0; i < 256 * 128; i += stride) woB[i] = f2bf(wo[i]);
  for (int i = i0; i < 128; i += stride) bqs[i] = bq[i] * QSCL;
}

// ---------------- MFMA Q + K/V projections (unchanged from R12) ----------------
__global__ __launch_bounds__(512, 2) void qkvproj(const float* __restrict__ met,
                                                  const float* __restrict__ ter,
                                                  const u16* __restrict__ wqB,
                                                  const float* __restrict__ bqs,
                                                  const u16* __restrict__ wkB,
                                                  const float* __restrict__ bk,
                                                  const u16* __restrict__ wvB,
                                                  const float* __restrict__ bv,
                                                  u16* __restrict__ Qtm,
                                                  u16* __restrict__ Ktm,
                                                  u16* __restrict__ Vcm) {
  const int tid = threadIdx.x;
  const int w = tid >> 6;
  const int lane = tid & 63;
  const int l31 = lane & 31;
  const int h = lane >> 5;

  if (blockIdx.x < 200) {
    const int b = blockIdx.x / 50;
    const int tokb = (blockIdx.x % 50) * 128;
    const int chg = (w & 3) * 32;
    const int half = w >> 2;
    const u16* wb = wqB + (size_t)(chg + l31) * 256 + h * 8;
    sh8 af[16];
#pragma unroll
    for (int kk = 0; kk < 16; kk++) af[kk] = *(const sh8*)(wb + kk * 16);
    float bias[16];
#pragma unroll
    for (int r = 0; r < 16; r++) bias[r] = bqs[chg + (r & 3) + 8 * (r >> 2) + 4 * h];
    const float* mp = met + (size_t)b * CMv * NTOK;
#pragma unroll
    for (int ct = 0; ct < 2; ct++) {
      const int tok = tokb + (half * 2 + ct) * 32 + l31;
      f32x16 acc = zero16();
#pragma unroll
      for (int kk = 0; kk < 16; kk++) {
        const float* cp = mp + (size_t)(kk * 16 + 8 * h) * NTOK + tok;
        float x0 = cp[0], x1 = cp[(size_t)NTOK], x2 = cp[(size_t)2 * NTOK],
              x3 = cp[(size_t)3 * NTOK], x4 = cp[(size_t)4 * NTOK],
              x5 = cp[(size_t)5 * NTOK], x6 = cp[(size_t)6 * NTOK],
              x7 = cp[(size_t)7 * NTOK];
        uint4v u = {pk2(x0, x1), pk2(x2, x3), pk2(x4, x5), pk2(x6, x7)};
        acc = __builtin_amdgcn_mfma_f32_32x32x16_bf16(
            af[kk], __builtin_bit_cast(sh8, u), acc, 0, 0, 0);
      }
      u16* qp = Qtm + ((size_t)b * NTOK + tok) * CAv;
#pragma unroll
      for (int rq = 0; rq < 4; rq++) {
        const int ch0 = chg + 8 * rq + 4 * h;
        uint2v d = {pk2(acc[4 * rq + 0] + bias[4 * rq + 0],
                        acc[4 * rq + 1] + bias[4 * rq + 1]),
                    pk2(acc[4 * rq + 2] + bias[4 * rq + 2],
                        acc[4 * rq + 3] + bias[4 * rq + 3])};
        *(uint2v*)(qp + ch0) = d;
      }
    }
  } else {
    const int bx = blockIdx.x - 200;
    const int b = bx / 50;
    const int tokb = (bx % 50) * 128;
    const bool isV = w >= 4;
    const int chg = (w & 3) * 32;
    const u16* wb = (isV ? wvB : wkB) + (size_t)(chg + l31) * 64 + h * 8;
    sh8 af[4];
#pragma unroll
    for (int kk = 0; kk < 4; kk++) af[kk] = *(const sh8*)(wb + kk * 16);
    const float* barr = isV ? bv : bk;
    float bias[16];
#pragma unroll
    for (int r = 0; r < 16; r++) bias[r] = barr[chg + (r & 3) + 8 * (r >> 2) + 4 * h];
    const float* tp = ter + (size_t)b * CTv * NTOK;
#pragma unroll
    for (int ct = 0; ct < 4; ct++) {
      const int tok = tokb + ct * 32 + l31;
      f32x16 acc = zero16();
#pragma unroll
      for (int kk = 0; kk < 4; kk++) {
        const float* cp = tp + (size_t)(kk * 16 + 8 * h) * NTOK + tok;
        float x0 = cp[0], x1 = cp[(size_t)NTOK], x2 = cp[(size_t)2 * NTOK],
              x3 = cp[(size_t)3 * NTOK], x4 = cp[(size_t)4 * NTOK],
              x5 = cp[(size_t)5 * NTOK], x6 = cp[(size_t)6 * NTOK],
              x7 = cp[(size_t)7 * NTOK];
        uint4v u = {pk2(x0, x1), pk2(x2, x3), pk2(x4, x5), pk2(x6, x7)};
        acc = __builtin_amdgcn_mfma_f32_32x32x16_bf16(
            af[kk], __builtin_bit_cast(sh8, u), acc, 0, 0, 0);
      }
      if (!isV) {
        u16* kp = Ktm + ((size_t)b * NTOK + tok) * CAv;
#pragma unroll
        for (int rq = 0; rq < 4; rq++) {
          const int ch0 = chg + 8 * rq + 4 * h;
          uint2v d = {pk2(acc[4 * rq + 0] + bias[4 * rq + 0],
                          acc[4 * rq + 1] + bias[4 * rq + 1]),
                      pk2(acc[4 * rq + 2] + bias[4 * rq + 2],
                          acc[4 * rq + 3] + bias[4 * rq + 3])};
          *(uint2v*)(kp + ch0) = d;
        }
      } else {
#pragma unroll
        for (int r = 0; r < 16; r++) {
          const int ch = chg + (r & 3) + 8 * (r >> 2) + 4 * h;
          Vcm[((size_t)b * CAv + ch) * NTOK + tok] = f2bf(acc[r] + bias[r]);
        }
      }
    }
  }
}

// ---------------- flash attention: 1-deep software pipeline ----------------
// Same math/swizzles as R11/R12. NEW: K triple-buffered (3x16KB), V double-
// buffered (2x16KB) = 80KB LDS (2 blocks/CU). Per iter t: stage K(t+2)+V(t+1),
// issue QK(t+1) -> s_next, then softmax(s_prev) runs on the VALU *under* those
// MFMAs (independent), then PV(t). One vmcnt(0)+barrier per tile.
__global__ __launch_bounds__(512, 2) void attn(const u16* __restrict__ Qtm,
                                               const u16* __restrict__ Ktm,
                                               const u16* __restrict__ Vcm,
                                               u16* __restrict__ Opart,
                                               float* __restrict__ Lpart) {
  __shared__ __align__(16) unsigned char smem[81920];  // K[3]@0, V[2]@49152

  const int tid = threadIdx.x;
  const int w = tid >> 6;
  const int lane = tid & 63;
  const int l31 = lane & 31;
  const int h = lane >> 5;

  const int g = blockIdx.x % 20;
  const int qt = blockIdx.x / 20;
  const int b = g / KVSPLIT;
  const int kvq = g % KVSPLIT;
  const int qb0 = qt * 256;
  const int kv00 = kvq * KVRANGE;

  const u16* Qb = Qtm + ((size_t)b * NTOK + qb0 + w * 32 + l31) * CAv;
  const u16* Kb = Ktm + (size_t)b * NTOK * CAv;
  const u16* Vb = Vcm + (size_t)b * CAv * NTOK;

  sh8 qf[8];
#pragma unroll
  for (int kk = 0; kk < 8; kk++) qf[kk] = *(const sh8*)(Qb + kk * 16 + h * 8);

  const int kr0 = w * 8 + (lane >> 4);
  const int kr1 = kr0 + 4;
  const u16* ksrc0 = Kb + ((size_t)kv00 + kr0) * CAv + (((lane & 15) ^ (kr0 & 15)) * 8);
  const u16* ksrc1 = Kb + ((size_t)kv00 + kr1) * CAv + (((lane & 15) ^ (kr1 & 15)) * 8);
  const int vc = w * 16 + (lane >> 3);
  const u16* vsrc = Vb + (size_t)vc * NTOK + kv00 +
                    (((lane & 7) ^ ((lane >> 3) & 7)) * 8);

  int koff[8];
#pragma unroll
  for (int kk = 0; kk < 8; kk++)
    koff[kk] = l31 * 256 + (((2 * kk + h) ^ (l31 & 15)) << 4);
  int voff[4];
#pragma unroll
  for (int b2 = 0; b2 < 4; b2++)
    voff[b2] = l31 * 128 + (((2 * b2 + h) ^ (l31 & 7)) << 4);

#define STAGE_K(p)                                       \
  do {                                                   \
    u16* kb_ = (u16*)(smem + (p) * 16384) + w * 1024;    \
    gl_lds16(ksrc0, kb_);                                \
    gl_lds16(ksrc1, kb_ + 512);                          \
    ksrc0 += 64 * CAv;                                   \
    ksrc1 += 64 * CAv;                                   \
  } while (0)
#define STAGE_V(v)                                               \
  do {                                                           \
    u16* vb_ = (u16*)(smem + 49152 + (v) * 16384) + w * 1024;    \
    gl_lds16(vsrc, vb_);                                         \
    gl_lds16(vsrc + (size_t)8 * NTOK, vb_ + 512);                \
    vsrc += 64;                                                  \
  } while (0)

  // prologue: K0, V0, K1 staged; confirm; QK(0)
  STAGE_K(0);
  STAGE_V(0);
  STAGE_K(1);
  asm volatile("s_waitcnt vmcnt(0)" ::: "memory");
  __builtin_amdgcn_s_barrier();

  f32x16 sp0 = zero16(), sp1 = zero16();
  {
    const unsigned char* kbuf = smem;  // K buf 0
    __builtin_amdgcn_s_setprio(1);
#pragma unroll
    for (int kk = 0; kk < 8; kk++) {
      sh8 kfa = *(const sh8*)(kbuf + koff[kk]);
      sh8 kfb = *(const sh8*)(kbuf + 8192 + koff[kk]);
      sp0 = __builtin_amdgcn_mfma_f32_32x32x16_bf16(kfa, qf[kk], sp0, 0, 0, 0);
      sp1 = __builtin_amdgcn_mfma_f32_32x32x16_bf16(kfb, qf[kk], sp1, 0, 0, 0);
    }
    __builtin_amdgcn_s_setprio(0);
  }

  f32x16 o[4];
#pragma unroll
  for (int i = 0; i < 4; i++) o[i] = zero16();
  float lsum = 0.f;

  int kqbuf = 1;  // K buffer for QK(t+1)
  int ksbuf = 2;  // K buffer being staged (t+2)
  for (int t = 0; t < NTILES; t++) {
    if (t < NTILES - 2) STAGE_K(ksbuf);
    if (t < NTILES - 1) STAGE_V((t + 1) & 1);
    // QK(t+1) -> s_next; softmax(s_prev) below is independent -> overlaps
    f32x16 sn0, sn1;
    if (t < NTILES - 1) {
      sn0 = zero16();
      sn1 = zero16();
      const unsigned char* kbuf = smem + kqbuf * 16384;
      __builtin_amdgcn_s_setprio(1);
#pragma unroll
      for (int kk = 0; kk < 8; kk++) {
        sh8 kfa = *(const sh8*)(kbuf + koff[kk]);
        sh8 kfb = *(const sh8*)(kbuf + 8192 + koff[kk]);
        sn0 = __builtin_amdgcn_mfma_f32_32x32x16_bf16(kfa, qf[kk], sn0, 0, 0, 0);
        sn1 = __builtin_amdgcn_mfma_f32_32x32x16_bf16(kfb, qf[kk], sn1, 0, 0, 0);
      }
      __builtin_amdgcn_s_setprio(0);
    }
    // static-C softmax on s_prev: P = exp2(S)
    f32x16 p0, p1;
#pragma unroll
    for (int r = 0; r < 16; r++) {
      p0[r] = __builtin_exp2f(sp0[r]);
      p1[r] = __builtin_exp2f(sp1[r]);
    }
#pragma unroll
    for (int r = 0; r < 16; r++) lsum += p0[r] + p1[r];
    unsigned pkm0[4][2], pkm1[4][2];
#pragma unroll
    for (int rq = 0; rq < 4; rq++) {
      pkm0[rq][0] = pk2(p0[4 * rq + 0], p0[4 * rq + 1]);
      pkm0[rq][1] = pk2(p0[4 * rq + 2], p0[4 * rq + 3]);
      pkm1[rq][0] = pk2(p1[4 * rq + 0], p1[4 * rq + 1]);
      pkm1[rq][1] = pk2(p1[4 * rq + 2], p1[4 * rq + 3]);
    }
    // PV(t) from V buffer t&1
    const unsigned char* vbuf = smem + 49152 + (t & 1) * 16384;
#pragma unroll
    for (int x = 0; x < 2; x++) {
#pragma unroll
      for (int b2i = 0; b2i < 2; b2i++) {
        unsigned ow0, ow1, sd0, sd1;
        if (x == 0) {
          ow0 = h ? pkm0[2 * b2i + 1][0] : pkm0[2 * b2i][0];
          ow1 = h ? pkm0[2 * b2i + 1][1] : pkm0[2 * b2i][1];
          sd0 = h ? pkm0[2 * b2i][0] : pkm0[2 * b2i + 1][0];
          sd1 = h ? pkm0[2 * b2i][1] : pkm0[2 * b2i + 1][1];
        } else {
          ow0 = h ? pkm1[2 * b2i + 1][0] : pkm1[2 * b2i][0];
          ow1 = h ? pkm1[2 * b2i + 1][1] : pkm1[2 * b2i][1];
          sd0 = h ? pkm1[2 * b2i][0] : pkm1[2 * b2i + 1][0];
          sd1 = h ? pkm1[2 * b2i][1] : pkm1[2 * b2i + 1][1];
        }
        unsigned rv0 = (unsigned)__shfl_xor((int)sd0, 32);
        unsigned rv1 = (unsigned)__shfl_xor((int)sd1, 32);
        uint4v fw = {h ? rv0 : ow0, h ? rv1 : ow1, h ? ow0 : rv0, h ? ow1 : rv1};
        sh8 pf = __builtin_bit_cast(sh8, fw);
        const int b2 = x * 2 + b2i;
        __builtin_amdgcn_s_setprio(1);
#pragma unroll
        for (int ct = 0; ct < 4; ct++) {
          sh8 vf = *(const sh8*)(vbuf + ct * 4096 + voff[b2]);
          o[ct] = __builtin_amdgcn_mfma_f32_32x32x16_bf16(vf, pf, o[ct], 0, 0, 0);
        }
        __builtin_amdgcn_s_setprio(0);
      }
    }
    // confirm K(t+2)/V(t+1) DMA (full compute phase to land); publish
    asm volatile("s_waitcnt vmcnt(0)" ::: "memory");
    __builtin_amdgcn_s_barrier();
    if (t < NTILES - 1) {
      sp0 = sn0;
      sp1 = sn1;
    }
    kqbuf = (kqbuf == 2) ? 0 : kqbuf + 1;
    ksbuf = (ksbuf == 2) ? 0 : ksbuf + 1;
  }
#undef STAGE_K
#undef STAGE_V

  // epilogue: one lsum hop, store unnormalized partial O (bf16) + l
  lsum += __shfl_xor(lsum, 32);
  u16* op = Opart + (((size_t)kvq * BB + b) * NTOK + qb0 + w * 32 + l31) * CAv;
#pragma unroll
  for (int ct = 0; ct < 4; ct++)
#pragma unroll
    for (int rq = 0; rq < 4; rq++) {
      uint2v d = {pk2(o[ct][4 * rq + 0], o[ct][4 * rq + 1]),
                  pk2(o[ct][4 * rq + 2], o[ct][4 * rq + 3])};
      *(uint2v*)(op + ct * 32 + rq * 8 + h * 4) = d;
    }
  if (h == 0) {
    size_t mi = ((size_t)kvq * BB + b) * NTOK + qb0 + w * 32 + l31;
    Lpart[mi] = lsum;
  }
}

// ---------------- MFMA output projection + merge + residual (unchanged) ----------------
__global__ __launch_bounds__(512, 2) void outproj(const float* __restrict__ met,
                                                  const u16* __restrict__ woB,
                                                  const float* __restrict__ bo,
                                                  const u16* __restrict__ Opart,
                                                  const float* __restrict__ Lpart,
                                                  float* __restrict__ out) {
  const int tid = threadIdx.x;
  const int w = tid >> 6;
  const int lane = tid & 63;
  const int l31 = lane & 31;
  const int h = lane >> 5;

  const int b = blockIdx.x / 100;
  const int tokb = (blockIdx.x % 100) * 64;
  const int chg = (w & 3) * 64;
  const int ct = w >> 2;
  const int tok = tokb + ct * 32 + l31;
  const size_t n = (size_t)b * NTOK + tok;
  const size_t PSTR = (size_t)BB * NTOK;

  const u16* wb0 = woB + (size_t)(chg + l31) * 128 + h * 8;
  const u16* wb1 = woB + (size_t)(chg + 32 + l31) * 128 + h * 8;
  sh8 a0[8], a1[8];
#pragma unroll
  for (int kk = 0; kk < 8; kk++) {
    a0[kk] = *(const sh8*)(wb0 + kk * 16);
    a1[kk] = *(const sh8*)(wb1 + kk * 16);
  }

  float L = 0.f;
#pragma unroll
  for (int i = 0; i < KVSPLIT; i++) L += Lpart[i * PSTR + n];
  const float rL = 1.f / L;

  f32x16 acc0 = zero16(), acc1 = zero16();
#pragma unroll
  for (int kk = 0; kk < 8; kk++) {
    float s[8];
#pragma unroll
    for (int j = 0; j < 8; j++) s[j] = 0.f;
#pragma unroll
    for (int i = 0; i < KVSPLIT; i++) {
      sh8 v = *(const sh8*)(Opart + (i * PSTR + n) * CAv + kk * 16 + 8 * h);
#pragma unroll
      for (int j = 0; j < 8; j++) s[j] += bf2f((u16)v[j]);
    }
    uint4v u = {pk2(s[0] * rL, s[1] * rL), pk2(s[2] * rL, s[3] * rL),
                pk2(s[4] * rL, s[5] * rL), pk2(s[6] * rL, s[7] * rL)};
    sh8 bf = __builtin_bit_cast(sh8, u);
    acc0 = __builtin_amdgcn_mfma_f32_32x32x16_bf16(a0[kk], bf, acc0, 0, 0, 0);
    acc1 = __builtin_amdgcn_mfma_f32_32x32x16_bf16(a1[kk], bf, acc1, 0, 0, 0);
  }
#pragma unroll
  for (int r = 0; r < 16; r++) {
    const int ro = (r & 3) + 8 * (r >> 2) + 4 * h;
    const int ch0 = chg + ro;
    const int ch1 = chg + 32 + ro;
    size_t i0 = ((size_t)b * CMv + ch0) * NTOK + tok;
    size_t i1 = ((size_t)b * CMv + ch1) * NTOK + tok;
    out[i0] = met[i0] + acc0[r] + bo[ch0];
    out[i1] = met[i1] + acc1[r] + bo[ch1];
  }
}

extern "C" void kernel_launch(void* const* d_in, const int* in_sizes, int n_in,
                              void* d_out, int out_size, void* d_ws, size_t ws_size,
                              hipStream_t stream) {
  const float* met = (const float*)d_in[0];
  const float* ter = (const float*)d_in[1];
  const float* wq = (const float*)d_in[2];
  const float* bq = (const float*)d_in[3];
  const float* wk = (const float*)d_in[4];
  const float* bk = (const float*)d_in[5];
  const float* wv = (const float*)d_in[6];
  const float* bv = (const float*)d_in[7];
  const float* wo = (const float*)d_in[8];
  const float* bo = (const float*)d_in[9];
  float* out = (float*)d_out;

  u16* Qtm = (u16*)d_ws;
  u16* Ktm = Qtm + (size_t)BB * NTOK * CAv;
  u16* Vcm = Ktm + (size_t)BB * NTOK * CAv;
  u16* Opart = Vcm + (size_t)BB * NTOK * CAv;
  float* Lpart = (float*)(Opart + (size_t)KVSPLIT * BB * NTOK * CAv);
  u16* wqB = (u16*)(Lpart + (size_t)KVSPLIT * BB * NTOK);
  u16* wkB = wqB + 128 * 256;
  u16* wvB = wkB + 128 * 64;
  u16* woB = wvB + 128 * 64;
  float* bqs = (float*)(woB + 256 * 128);

  prep<<<dim3(40), dim3(256), 0, stream>>>(wq, bq, wk, wv, wo, wqB, bqs, wkB, wvB, woB);
  qkvproj<<<dim3(400), dim3(512), 0, stream>>>(met, ter, wqB, bqs, wkB, bk,
                                               wvB, bv, Qtm, Ktm, Vcm);
  attn<<<dim3(500), dim3(512), 0, stream>>>(Qtm, Ktm, Vcm, Opart, Lpart);
  outproj<<<dim3(400), dim3(512), 0, stream>>>(met, woB, bo, Opart, Lpart, out);
}

// Round 14
// 171.405 us; speedup vs baseline: 1.0779x; 1.0779x over previous
//
#include <hip/hip_runtime.h>
#include <hip/hip_bf16.h>

#define BB 4
#define CMv 256
#define CTv 64
#define CAv 128
#define NTOK 6400
#define KVSPLIT 5
#define KVRANGE 1280   /* NTOK/KVSPLIT */
#define NTILES 20      /* KVRANGE/64 */
/* 128^-0.5 * log2(e): softmax runs in exp2 domain */
#define QSCL 0.12753102198064644f

typedef unsigned short u16;
typedef __attribute__((ext_vector_type(8))) short sh8;     // 8 bf16
typedef __attribute__((ext_vector_type(4))) float f32x4;
typedef __attribute__((ext_vector_type(16))) float f32x16;
typedef __attribute__((ext_vector_type(4))) unsigned uint4v;
typedef __attribute__((ext_vector_type(2))) unsigned uint2v;

__device__ __forceinline__ u16 f2bf(float f) {
  return __builtin_bit_cast(u16, __float2bfloat16(f));
}
__device__ __forceinline__ float bf2f(u16 x) {
  unsigned u = ((unsigned)x) << 16;
  return __builtin_bit_cast(float, u);
}
// packed bf16 pair via HW convert (RNE), T12 recipe: dst[15:0]=bf16(a), dst[31:16]=bf16(b)
__device__ __forceinline__ unsigned pk2(float a, float b) {
  unsigned r;
  asm("v_cvt_pk_bf16_f32 %0, %1, %2" : "=v"(r) : "v"(a), "v"(b));
  return r;
}
__device__ __forceinline__ f32x16 zero16() {
  f32x16 z;
#pragma unroll
  for (int i = 0; i < 16; i++) z[i] = 0.f;
  return z;
}
typedef const __attribute__((address_space(1))) unsigned int* gas_p;
typedef __attribute__((address_space(3))) unsigned int* las_p;
__device__ __forceinline__ void gl_lds16(const u16* g, u16* l) {
  __builtin_amdgcn_global_load_lds((gas_p)g, (las_p)l, 16, 0, 0);
}

// ---------------- weight prep: fp32 -> bf16, row-major (A-frag ready) ----------------
__global__ __launch_bounds__(256) void prep(const float* __restrict__ wq,
                                            const float* __restrict__ bq,
                                            const float* __restrict__ wk,
                                            const float* __restrict__ wv,
                                            const float* __restrict__ wo,
                                            u16* __restrict__ wqB,
                                            float* __restrict__ bqs,
                                            u16* __restrict__ wkB,
                                            u16* __restrict__ wvB,
                                            u16* __restrict__ woB) {
  const int i0 = blockIdx.x * 256 + threadIdx.x;
  const int stride = gridDim.x * 256;
  for (int i = i0; i < 128 * 256; i += stride) wqB[i] = f2bf(wq[i] * QSCL);
  for (int i = i0; i < 128 * 64; i += stride) { wkB[i] = f2bf(wk[i]); wvB[i] = f2bf(wv[i]); }
  for (int i = i0; i < 256 * 128; i += stride) woB[i] = f2bf(wo[i]);
  for (int i = i0; i < 128; i += stride) bqs[i] = bq[i] * QSCL;
}

// ---------------- MFMA Q + K/V projections ----------------
__global__ __launch_bounds__(512, 2) void qkvproj(const float* __restrict__ met,
                                                  const float* __restrict__ ter,
                                                  const u16* __restrict__ wqB,
                                                  const float* __restrict__ bqs,
                                                  const u16* __restrict__ wkB,
                                                  const float* __restrict__ bk,
                                                  const u16* __restrict__ wvB,
                                                  const float* __restrict__ bv,
                                                  u16* __restrict__ Qtm,
                                                  u16* __restrict__ Ktm,
                                                  u16* __restrict__ Vcm) {
  const int tid = threadIdx.x;
  const int w = tid >> 6;
  const int lane = tid & 63;
  const int l31 = lane & 31;
  const int h = lane >> 5;

  if (blockIdx.x < 200) {
    const int b = blockIdx.x / 50;
    const int tokb = (blockIdx.x % 50) * 128;
    const int chg = (w & 3) * 32;
    const int half = w >> 2;
    const u16* wb = wqB + (size_t)(chg + l31) * 256 + h * 8;
    sh8 af[16];
#pragma unroll
    for (int kk = 0; kk < 16; kk++) af[kk] = *(const sh8*)(wb + kk * 16);
    float bias[16];
#pragma unroll
    for (int r = 0; r < 16; r++) bias[r] = bqs[chg + (r & 3) + 8 * (r >> 2) + 4 * h];
    const float* mp = met + (size_t)b * CMv * NTOK;
#pragma unroll
    for (int ct = 0; ct < 2; ct++) {
      const int tok = tokb + (half * 2 + ct) * 32 + l31;
      f32x16 acc = zero16();
#pragma unroll
      for (int kk = 0; kk < 16; kk++) {
        const float* cp = mp + (size_t)(kk * 16 + 8 * h) * NTOK + tok;
        float x0 = cp[0], x1 = cp[(size_t)NTOK], x2 = cp[(size_t)2 * NTOK],
              x3 = cp[(size_t)3 * NTOK], x4 = cp[(size_t)4 * NTOK],
              x5 = cp[(size_t)5 * NTOK], x6 = cp[(size_t)6 * NTOK],
              x7 = cp[(size_t)7 * NTOK];
        uint4v u = {pk2(x0, x1), pk2(x2, x3), pk2(x4, x5), pk2(x6, x7)};
        acc = __builtin_amdgcn_mfma_f32_32x32x16_bf16(
            af[kk], __builtin_bit_cast(sh8, u), acc, 0, 0, 0);
      }
      u16* qp = Qtm + ((size_t)b * NTOK + tok) * CAv;
#pragma unroll
      for (int rq = 0; rq < 4; rq++) {
        const int ch0 = chg + 8 * rq + 4 * h;
        uint2v d = {pk2(acc[4 * rq + 0] + bias[4 * rq + 0],
                        acc[4 * rq + 1] + bias[4 * rq + 1]),
                    pk2(acc[4 * rq + 2] + bias[4 * rq + 2],
                        acc[4 * rq + 3] + bias[4 * rq + 3])};
        *(uint2v*)(qp + ch0) = d;
      }
    }
  } else {
    const int bx = blockIdx.x - 200;
    const int b = bx / 50;
    const int tokb = (bx % 50) * 128;
    const bool isV = w >= 4;
    const int chg = (w & 3) * 32;
    const u16* wb = (isV ? wvB : wkB) + (size_t)(chg + l31) * 64 + h * 8;
    sh8 af[4];
#pragma unroll
    for (int kk = 0; kk < 4; kk++) af[kk] = *(const sh8*)(wb + kk * 16);
    const float* barr = isV ? bv : bk;
    float bias[16];
#pragma unroll
    for (int r = 0; r < 16; r++) bias[r] = barr[chg + (r & 3) + 8 * (r >> 2) + 4 * h];
    const float* tp = ter + (size_t)b * CTv * NTOK;
#pragma unroll
    for (int ct = 0; ct < 4; ct++) {
      const int tok = tokb + ct * 32 + l31;
      f32x16 acc = zero16();
#pragma unroll
      for (int kk = 0; kk < 4; kk++) {
        const float* cp = tp + (size_t)(kk * 16 + 8 * h) * NTOK + tok;
        float x0 = cp[0], x1 = cp[(size_t)NTOK], x2 = cp[(size_t)2 * NTOK],
              x3 = cp[(size_t)3 * NTOK], x4 = cp[(size_t)4 * NTOK],
              x5 = cp[(size_t)5 * NTOK], x6 = cp[(size_t)6 * NTOK],
              x7 = cp[(size_t)7 * NTOK];
        uint4v u = {pk2(x0, x1), pk2(x2, x3), pk2(x4, x5), pk2(x6, x7)};
        acc = __builtin_amdgcn_mfma_f32_32x32x16_bf16(
            af[kk], __builtin_bit_cast(sh8, u), acc, 0, 0, 0);
      }
      if (!isV) {
        u16* kp = Ktm + ((size_t)b * NTOK + tok) * CAv;
#pragma unroll
        for (int rq = 0; rq < 4; rq++) {
          const int ch0 = chg + 8 * rq + 4 * h;
          uint2v d = {pk2(acc[4 * rq + 0] + bias[4 * rq + 0],
                          acc[4 * rq + 1] + bias[4 * rq + 1]),
                      pk2(acc[4 * rq + 2] + bias[4 * rq + 2],
                          acc[4 * rq + 3] + bias[4 * rq + 3])};
          *(uint2v*)(kp + ch0) = d;
        }
      } else {
#pragma unroll
        for (int r = 0; r < 16; r++) {
          const int ch = chg + (r & 3) + 8 * (r >> 2) + 4 * h;
          Vcm[((size_t)b * CAv + ch) * NTOK + tok] = f2bf(acc[r] + bias[r]);
        }
      }
    }
  }
}

// ---------------- flash attention (R11 loop + XCD-contiguous remap) ----------------
// Grid 500. bid remap: XCD x = bid&7 gets a CONTIGUOUS work range W so each
// XCD-L2 holds only ~2.5 K/V segments (~1.6 MB, L2-resident) instead of ~5
// interleaved (3.2+ MB -> L3 round-trips). W = start(x) + bid>>3, bijective.
// Block: 8 waves x 32 q-rows (Q_T=256), KVBLK=64, 2x32KB LDS double-buffer
// via global_load_lds (1 ahead; vmcnt(0)+s_barrier per tile). Static-C
// softmax (P = exp2(S), no max tracking; merge = plain sum). K rows 256B XOR
// slot^(row&15); V rows 128B XOR slot^(c&7); per-instruction key match.
__global__ __launch_bounds__(512, 2) void attn(const u16* __restrict__ Qtm,
                                               const u16* __restrict__ Ktm,
                                               const u16* __restrict__ Vcm,
                                               u16* __restrict__ Opart,
                                               float* __restrict__ Lpart) {
  __shared__ __align__(16) unsigned char smem[65536];  // 2 x (K 16KB | V 16KB)

  const int tid = threadIdx.x;
  const int w = tid >> 6;
  const int lane = tid & 63;
  const int l31 = lane & 31;
  const int h = lane >> 5;

  // XCD-contiguous remap (500 = 8*62 + 4: XCDs 0-3 get 63 blocks, 4-7 get 62)
  const int x = blockIdx.x & 7;
  const int W = x * 62 + (x < 4 ? x : 4) + (blockIdx.x >> 3);
  const int g = W / 25;        // segment 0..19 (b*5 + kvq)
  const int qt = W % 25;
  const int b = g / KVSPLIT;
  const int kvq = g % KVSPLIT;
  const int qb0 = qt * 256;
  const int kv00 = kvq * KVRANGE;

  const u16* Qb = Qtm + ((size_t)b * NTOK + qb0 + w * 32 + l31) * CAv;
  const u16* Kb = Ktm + (size_t)b * NTOK * CAv;
  const u16* Vb = Vcm + (size_t)b * CAv * NTOK;

  sh8 qf[8];
#pragma unroll
  for (int kk = 0; kk < 8; kk++) qf[kk] = *(const sh8*)(Qb + kk * 16 + h * 8);

  const int kr0 = w * 8 + (lane >> 4);
  const int kr1 = kr0 + 4;
  const u16* ksrc0 = Kb + ((size_t)kv00 + kr0) * CAv + (((lane & 15) ^ (kr0 & 15)) * 8);
  const u16* ksrc1 = Kb + ((size_t)kv00 + kr1) * CAv + (((lane & 15) ^ (kr1 & 15)) * 8);
  const int vc = w * 16 + (lane >> 3);
  const u16* vsrc = Vb + (size_t)vc * NTOK + kv00 +
                    (((lane & 7) ^ ((lane >> 3) & 7)) * 8);

  int koff[8];
#pragma unroll
  for (int kk = 0; kk < 8; kk++)
    koff[kk] = l31 * 256 + (((2 * kk + h) ^ (l31 & 15)) << 4);
  int voff[4];
#pragma unroll
  for (int b2 = 0; b2 < 4; b2++)
    voff[b2] = l31 * 128 + (((2 * b2 + h) ^ (l31 & 7)) << 4);

#define STAGE(p)                                               \
  do {                                                         \
    u16* kb_ = (u16*)(smem + (p) * 32768) + w * 1024;          \
    gl_lds16(ksrc0, kb_);                                      \
    gl_lds16(ksrc1, kb_ + 512);                                \
    u16* vb_ = (u16*)(smem + (p) * 32768 + 16384) + w * 1024;  \
    gl_lds16(vsrc, vb_);                                       \
    gl_lds16(vsrc + (size_t)8 * NTOK, vb_ + 512);              \
    ksrc0 += 64 * CAv;                                         \
    ksrc1 += 64 * CAv;                                         \
    vsrc += 64;                                                \
  } while (0)

  STAGE(0);
  asm volatile("s_waitcnt vmcnt(0)" ::: "memory");
  __builtin_amdgcn_s_barrier();

  f32x16 o[4];
#pragma unroll
  for (int i = 0; i < 4; i++) o[i] = zero16();
  float lsum = 0.f;

  int buf = 0;
  for (int t = 0; t < NTILES; t++) {
    if (t < NTILES - 1) STAGE(buf ^ 1);
    const unsigned char* kbuf = smem + buf * 32768;
    const unsigned char* vbuf = kbuf + 16384;
    __builtin_amdgcn_s_setprio(1);
    f32x16 s0 = zero16(), s1 = zero16();
#pragma unroll
    for (int kk = 0; kk < 8; kk++) {
      sh8 kfa = *(const sh8*)(kbuf + koff[kk]);
      sh8 kfb = *(const sh8*)(kbuf + 8192 + koff[kk]);
      s0 = __builtin_amdgcn_mfma_f32_32x32x16_bf16(kfa, qf[kk], s0, 0, 0, 0);
      s1 = __builtin_amdgcn_mfma_f32_32x32x16_bf16(kfb, qf[kk], s1, 0, 0, 0);
    }
    __builtin_amdgcn_s_setprio(0);
    // static-C softmax: P = exp2(S); pack via v_cvt_pk (1 inst / 2 vals)
    f32x16 p0, p1;
#pragma unroll
    for (int r = 0; r < 16; r++) {
      p0[r] = __builtin_exp2f(s0[r]);
      p1[r] = __builtin_exp2f(s1[r]);
    }
#pragma unroll
    for (int r = 0; r < 16; r++) lsum += p0[r] + p1[r];
    unsigned pkm0[4][2], pkm1[4][2];
#pragma unroll
    for (int rq = 0; rq < 4; rq++) {
      pkm0[rq][0] = pk2(p0[4 * rq + 0], p0[4 * rq + 1]);
      pkm0[rq][1] = pk2(p0[4 * rq + 2], p0[4 * rq + 3]);
      pkm1[rq][0] = pk2(p1[4 * rq + 0], p1[4 * rq + 1]);
      pkm1[rq][1] = pk2(p1[4 * rq + 2], p1[4 * rq + 3]);
    }
#pragma unroll
    for (int xx = 0; xx < 2; xx++) {
#pragma unroll
      for (int b2i = 0; b2i < 2; b2i++) {
        unsigned ow0, ow1, sd0, sd1;
        if (xx == 0) {
          ow0 = h ? pkm0[2 * b2i + 1][0] : pkm0[2 * b2i][0];
          ow1 = h ? pkm0[2 * b2i + 1][1] : pkm0[2 * b2i][1];
          sd0 = h ? pkm0[2 * b2i][0] : pkm0[2 * b2i + 1][0];
          sd1 = h ? pkm0[2 * b2i][1] : pkm0[2 * b2i + 1][1];
        } else {
          ow0 = h ? pkm1[2 * b2i + 1][0] : pkm1[2 * b2i][0];
          ow1 = h ? pkm1[2 * b2i + 1][1] : pkm1[2 * b2i][1];
          sd0 = h ? pkm1[2 * b2i][0] : pkm1[2 * b2i + 1][0];
          sd1 = h ? pkm1[2 * b2i][1] : pkm1[2 * b2i + 1][1];
        }
        unsigned rv0 = (unsigned)__shfl_xor((int)sd0, 32);
        unsigned rv1 = (unsigned)__shfl_xor((int)sd1, 32);
        uint4v fw = {h ? rv0 : ow0, h ? rv1 : ow1, h ? ow0 : rv0, h ? ow1 : rv1};
        sh8 pf = __builtin_bit_cast(sh8, fw);
        const int b2 = xx * 2 + b2i;
        __builtin_amdgcn_s_setprio(1);
#pragma unroll
        for (int ct = 0; ct < 4; ct++) {
          sh8 vf = *(const sh8*)(vbuf + ct * 4096 + voff[b2]);
          o[ct] = __builtin_amdgcn_mfma_f32_32x32x16_bf16(vf, pf, o[ct], 0, 0, 0);
        }
        __builtin_amdgcn_s_setprio(0);
      }
    }
    asm volatile("s_waitcnt vmcnt(0)" ::: "memory");
    __builtin_amdgcn_s_barrier();
    buf ^= 1;
  }
#undef STAGE

  lsum += __shfl_xor(lsum, 32);
  u16* op = Opart + (((size_t)kvq * BB + b) * NTOK + qb0 + w * 32 + l31) * CAv;
#pragma unroll
  for (int ct = 0; ct < 4; ct++)
#pragma unroll
    for (int rq = 0; rq < 4; rq++) {
      uint2v d = {pk2(o[ct][4 * rq + 0], o[ct][4 * rq + 1]),
                  pk2(o[ct][4 * rq + 2], o[ct][4 * rq + 3])};
      *(uint2v*)(op + ct * 32 + rq * 8 + h * 4) = d;
    }
  if (h == 0) {
    size_t mi = ((size_t)kvq * BB + b) * NTOK + qb0 + w * 32 + l31;
    Lpart[mi] = lsum;
  }
}

// ---------------- MFMA output projection + merge + residual ----------------
__global__ __launch_bounds__(512, 2) void outproj(const float* __restrict__ met,
                                                  const u16* __restrict__ woB,
                                                  const float* __restrict__ bo,
                                                  const u16* __restrict__ Opart,
                                                  const float* __restrict__ Lpart,
                                                  float* __restrict__ out) {
  const int tid = threadIdx.x;
  const int w = tid >> 6;
  const int lane = tid & 63;
  const int l31 = lane & 31;
  const int h = lane >> 5;

  const int b = blockIdx.x / 100;
  const int tokb = (blockIdx.x % 100) * 64;
  const int chg = (w & 3) * 64;
  const int ct = w >> 2;
  const int tok = tokb + ct * 32 + l31;
  const size_t n = (size_t)b * NTOK + tok;
  const size_t PSTR = (size_t)BB * NTOK;

  const u16* wb0 = woB + (size_t)(chg + l31) * 128 + h * 8;
  const u16* wb1 = woB + (size_t)(chg + 32 + l31) * 128 + h * 8;
  sh8 a0[8], a1[8];
#pragma unroll
  for (int kk = 0; kk < 8; kk++) {
    a0[kk] = *(const sh8*)(wb0 + kk * 16);
    a1[kk] = *(const sh8*)(wb1 + kk * 16);
  }

  float L = 0.f;
#pragma unroll
  for (int i = 0; i < KVSPLIT; i++) L += Lpart[i * PSTR + n];
  const float rL = 1.f / L;

  f32x16 acc0 = zero16(), acc1 = zero16();
#pragma unroll
  for (int kk = 0; kk < 8; kk++) {
    float s[8];
#pragma unroll
    for (int j = 0; j < 8; j++) s[j] = 0.f;
#pragma unroll
    for (int i = 0; i < KVSPLIT; i++) {
      sh8 v = *(const sh8*)(Opart + (i * PSTR + n) * CAv + kk * 16 + 8 * h);
#pragma unroll
      for (int j = 0; j < 8; j++) s[j] += bf2f((u16)v[j]);
    }
    uint4v u = {pk2(s[0] * rL, s[1] * rL), pk2(s[2] * rL, s[3] * rL),
                pk2(s[4] * rL, s[5] * rL), pk2(s[6] * rL, s[7] * rL)};
    sh8 bf = __builtin_bit_cast(sh8, u);
    acc0 = __builtin_amdgcn_mfma_f32_32x32x16_bf16(a0[kk], bf, acc0, 0, 0, 0);
    acc1 = __builtin_amdgcn_mfma_f32_32x32x16_bf16(a1[kk], bf, acc1, 0, 0, 0);
  }
#pragma unroll
  for (int r = 0; r < 16; r++) {
    const int ro = (r & 3) + 8 * (r >> 2) + 4 * h;
    const int ch0 = chg + ro;
    const int ch1 = chg + 32 + ro;
    size_t i0 = ((size_t)b * CMv + ch0) * NTOK + tok;
    size_t i1 = ((size_t)b * CMv + ch1) * NTOK + tok;
    out[i0] = met[i0] + acc0[r] + bo[ch0];
    out[i1] = met[i1] + acc1[r] + bo[ch1];
  }
}

extern "C" void kernel_launch(void* const* d_in, const int* in_sizes, int n_in,
                              void* d_out, int out_size, void* d_ws, size_t ws_size,
                              hipStream_t stream) {
  const float* met = (const float*)d_in[0];
  const float* ter = (const float*)d_in[1];
  const float* wq = (const float*)d_in[2];
  const float* bq = (const float*)d_in[3];
  const float* wk = (const float*)d_in[4];
  const float* bk = (const float*)d_in[5];
  const float* wv = (const float*)d_in[6];
  const float* bv = (const float*)d_in[7];
  const float* wo = (const float*)d_in[8];
  const float* bo = (const float*)d_in[9];
  float* out = (float*)d_out;

  u16* Qtm = (u16*)d_ws;
  u16* Ktm = Qtm + (size_t)BB * NTOK * CAv;
  u16* Vcm = Ktm + (size_t)BB * NTOK * CAv;
  u16* Opart = Vcm + (size_t)BB * NTOK * CAv;
  float* Lpart = (float*)(Opart + (size_t)KVSPLIT * BB * NTOK * CAv);
  u16* wqB = (u16*)(Lpart + (size_t)KVSPLIT * BB * NTOK);
  u16* wkB = wqB + 128 * 256;
  u16* wvB = wkB + 128 * 64;
  u16* woB = wvB + 128 * 64;
  float* bqs = (float*)(woB + 256 * 128);

  prep<<<dim3(40), dim3(256), 0, stream>>>(wq, bq, wk, wv, wo, wqB, bqs, wkB, wvB, woB);
  qkvproj<<<dim3(400), dim3(512), 0, stream>>>(met, ter, wqB, bqs, wkB, bk,
                                               wvB, bv, Qtm, Ktm, Vcm);
  attn<<<dim3(500), dim3(512), 0, stream>>>(Qtm, Ktm, Vcm, Opart, Lpart);
  outproj<<<dim3(400), dim3(512), 0, stream>>>(met, woB, bo, Opart, Lpart, out);
}